// Round 5
// baseline (379.533 us; speedup 1.0000x reference)
//
#include <hip/hip_runtime.h>

// LinkPrediction: per-edge 2-layer MLP routed by edge type (MoE-style).
// outputs: [0..N_EDGES) = scores, [N_EDGES..) = copy of rgcn_emb.
//
// R8: SINGLE-KERNEL design. R0/R2/R4 all ~280us total with score=86-100us:
// the serialized {hist -> scan/scatter -> score} chain costs ~180us however
// the work is distributed; coop grid.sync was 300us/sync (R3). The global
// sort existed only for wave-uniform types -> replace with PER-BLOCK LDS
// bucketing: each block buckets a 1024-edge chunk by type into LDS slots,
// each bucket padded to 64 -> every wave spans exactly one bucket ->
// readfirstlane(type) + scalar W1 loads, same as sorted. ~25% lane padding
// waste, but ZERO prep dispatches, zero workspace, fp32 (no f16 table pass).
// Copy rides on dedicated blocks (proven free; warms LLC for gathers).

typedef float f4 __attribute__((ext_vector_type(4)));

constexpr int N_NODES = 200000;
constexpr int N_EDGES = 400000;
constexpr int EMB_DIM = 128;
constexpr int HID     = 24;
constexpr int N_TYPES = 8;
constexpr int BLK     = 256;

constexpr int E_CH     = 1024;                              // edges per block
constexpr int NCHUNK   = (N_EDGES + E_CH - 1) / E_CH;       // 391
constexpr int SLOT_MAX = E_CH + N_TYPES * 64;               // 1536 (64-pad/bucket)
constexpr int COPY_BLOCKS = 1024;

__device__ __forceinline__ void half_mm(const f4* __restrict__ x4,
                                        const float* __restrict__ w,
                                        float acc[HID]) {
#pragma unroll 1
    for (int c = 0; c < 4; ++c) {                           // 128B per chunk
        f4 r[8];
#pragma unroll
        for (int k = 0; k < 8; ++k) r[k] = x4[c * 8 + k];
#pragma unroll
        for (int k = 0; k < 8; ++k) {
            const float* wp = w + (c * 32 + k * 4) * HID;
#pragma unroll
            for (int j = 0; j < HID; ++j) acc[j] = fmaf(r[k][0], wp[0 * HID + j], acc[j]);
#pragma unroll
            for (int j = 0; j < HID; ++j) acc[j] = fmaf(r[k][1], wp[1 * HID + j], acc[j]);
#pragma unroll
            for (int j = 0; j < HID; ++j) acc[j] = fmaf(r[k][2], wp[2 * HID + j], acc[j]);
#pragma unroll
            for (int j = 0; j < HID; ++j) acc[j] = fmaf(r[k][3], wp[3 * HID + j], acc[j]);
        }
    }
}

__device__ __forceinline__ void do_copy(const float* __restrict__ emb,
                                        float* __restrict__ out, int cb, int nb) {
    const f4* s4 = (const f4*)emb;
    f4* o4 = (f4*)(out + N_EDGES);
    const int n4 = N_NODES * EMB_DIM / 4;                   // 6.4M
    for (int i = cb * BLK + (int)threadIdx.x; i < n4; i += nb * BLK) {
        f4 a = s4[i];                                       // normal: warms LLC
        __builtin_nontemporal_store(a, &o4[i]);             // never re-read
    }
}

__global__ __launch_bounds__(BLK) void fused_k(
        const float* __restrict__ emb,
        const int* __restrict__ srci, const int* __restrict__ dsti,
        const int* __restrict__ etype,
        const float* __restrict__ W1, const float* __restrict__ b1,
        const float* __restrict__ W2, const float* __restrict__ b2,
        float* __restrict__ out) {
    int b = blockIdx.x;
    if (b >= NCHUNK) {                                      // copy duty
        do_copy(emb, out, b - NCHUNK, (int)gridDim.x - NCHUNK);
        return;
    }

    // ---- per-block LDS bucketing by edge type ----
    __shared__ short slots[SLOT_MAX];
    __shared__ int cnt[N_TYPES], fill[N_TYPES], bstart[N_TYPES + 1];
    const int tid = (int)threadIdx.x;
    const int e0 = b * E_CH;
    const int n  = min(E_CH, N_EDGES - e0);

    if (tid < N_TYPES) cnt[tid] = 0;
    for (int s = tid; s < SLOT_MAX; s += BLK) slots[s] = -1;
    __syncthreads();
    for (int i = tid; i < n; i += BLK)
        atomicAdd(&cnt[etype[e0 + i]], 1);
    __syncthreads();
    if (tid == 0) {
        int off = 0;
#pragma unroll
        for (int t = 0; t < N_TYPES; ++t) {
            bstart[t] = off;
            off += ((cnt[t] + 63) / 64) * 64;               // pad bucket to wave
        }
        bstart[N_TYPES] = off;
    }
    if (tid < N_TYPES) fill[tid] = 0;
    __syncthreads();
    for (int i = tid; i < n; i += BLK) {
        int t = etype[e0 + i];
        int r = atomicAdd(&fill[t], 1);                     // LDS-local only
        slots[bstart[t] + r] = (short)i;
    }
    __syncthreads();

    // ---- process: each wave spans one 64-padded bucket -> uniform type ----
    const int nslots = bstart[N_TYPES];                     // <= 1528
    for (int s0 = 0; s0 < nslots; s0 += BLK) {
        int s = s0 + tid;                                   // wave: 64-aligned range
        int t = 0;
#pragma unroll
        for (int i = 1; i < N_TYPES; ++i)
            if (s >= bstart[i]) t = i;
        t = __builtin_amdgcn_readfirstlane(t);              // wave-uniform
        int si = (s < nslots) ? (int)slots[s] : -1;
        if (si >= 0) {
            int e = e0 + si;
            int sn = srci[e], dn = dsti[e];
            float acc[HID];
#pragma unroll
            for (int j = 0; j < HID; ++j) acc[j] = b1[t * HID + j];
            const float* W1t = W1 + (size_t)t * (2 * EMB_DIM * HID);
            half_mm((const f4*)(emb + (size_t)sn * EMB_DIM), W1t, acc);
            half_mm((const f4*)(emb + (size_t)dn * EMB_DIM), W1t + EMB_DIM * HID, acc);
            float sc = b2[t];
#pragma unroll
            for (int j = 0; j < HID; ++j) {
                float h = acc[j];
                h = (h > 0.f) ? h : 0.01f * h;              // LeakyReLU(0.01)
                sc = fmaf(h, W2[t * HID + j], sc);
            }
            out[e] = sc;
        }
    }
}

extern "C" void kernel_launch(void* const* d_in, const int* in_sizes, int n_in,
                              void* d_out, int out_size, void* d_ws, size_t ws_size,
                              hipStream_t stream) {
    const float* emb   = (const float*)d_in[0];
    const int*   eidx  = (const int*)d_in[1];
    const int*   etype = (const int*)d_in[2];
    const float* W1    = (const float*)d_in[3];
    const float* b1    = (const float*)d_in[4];
    const float* W2    = (const float*)d_in[5];
    const float* b2    = (const float*)d_in[6];
    float* out = (float*)d_out;
    const int* srci = eidx;
    const int* dsti = eidx + N_EDGES;

    fused_k<<<NCHUNK + COPY_BLOCKS, BLK, 0, stream>>>(
        emb, srci, dsti, etype, W1, b1, W2, b2, out);
}

// Round 6
// 264.241 us; speedup vs baseline: 1.4363x; 1.4363x over previous
//
#include <hip/hip_runtime.h>

// LinkPrediction: per-edge 2-layer MLP routed by edge type (MoE-style).
// outputs: [0..N_EDGES) = scores, [N_EDGES..) = copy of rgcn_emb.
//
// R9. Six-round model: bench_total ~= 120us fixed overhead + SUM(kernels);
// dispatch count irrelevant (R0/R4/R5: 158+120, 160+120, 260+120).
// f16 emb table is NET-NEGATIVE: saves ~30us in score (86 vs 116) but costs
// ~50us of convert traffic. Local bucketing (R5): parallelism collapse.
// Coop grid.sync (R3): ~300us/sync. Minimum-SUM config of proven parts:
//  K1 hist_k:    int4 etype read, per-chunk LDS counts -> table (~3us)
//  K2 scatter_k: deterministic scan+scatter, no global atomics (~10us, R4)
//  K3 score32_k: sorted fp32 MLP (wave-uniform type -> scalar W1) + copy
//                fused on dedicated blocks (proven free, warms LLC) (~116us)

typedef float f4 __attribute__((ext_vector_type(4)));

constexpr int N_NODES = 200000;
constexpr int N_EDGES = 400000;
constexpr int EMB_DIM = 128;
constexpr int HID     = 24;
constexpr int N_TYPES = 8;
constexpr int BLK     = 256;

constexpr int CHUNKS  = 128;
constexpr int CH_SZ   = N_EDGES / CHUNKS;                  // 3125 exact
constexpr int MAX_PAD = N_EDGES + N_TYPES * (BLK - 1);     // 402040
constexpr int SCORE_BLOCKS = (MAX_PAD + BLK - 1) / BLK;    // 1571
constexpr int COPY_BLOCKS  = 1024;

// ws int offsets
constexpr int OFF_CC     = 0;                               // [CHUNKS*8]
constexpr int OFF_COUNTS = OFF_CC + CHUNKS * N_TYPES;       // [8]
constexpr int OFF_POFF   = OFF_COUNTS + N_TYPES;            // [8]
constexpr int OFF_SORTED = OFF_POFF + N_TYPES;              // [MAX_PAD]
constexpr size_t WS_NEED = (size_t)(OFF_SORTED + MAX_PAD) * sizeof(int);

// ---------- K1: per-chunk histogram (no atomics to global, no memset) ----------
__global__ __launch_bounds__(BLK) void hist_k(const int* __restrict__ etype,
                                              int* __restrict__ ws) {
    __shared__ int lc[N_TYPES];
    int b = blockIdx.x;
    if (threadIdx.x < N_TYPES) lc[threadIdx.x] = 0;
    __syncthreads();
    int e0 = b * CH_SZ;
    const int4* et4 = (const int4*)(etype + e0);            // CH_SZ%4 != 0? 3125/4: no
    // CH_SZ = 3125 not divisible by 4 -> scalar loop (1.6MB total, trivial)
    for (int e = e0 + (int)threadIdx.x; e < e0 + CH_SZ; e += BLK)
        atomicAdd(&lc[etype[e]], 1);
    (void)et4;
    __syncthreads();
    if (threadIdx.x < N_TYPES)
        ws[OFF_CC + b * N_TYPES + threadIdx.x] = lc[threadIdx.x];
}

// ---------- K2: deterministic scan + scatter (no global atomics) ----------
__global__ __launch_bounds__(BLK) void scatter_k(
        const int* __restrict__ etype, int* __restrict__ ws) {
    __shared__ int sbase[N_TYPES];  // poff[t] + prefix of this chunk
    __shared__ int tot[N_TYPES];
    __shared__ int mybase[N_TYPES];
    __shared__ int spoff[N_TYPES];
    __shared__ int lc[N_TYPES];
    int b = blockIdx.x;
    if (threadIdx.x < N_TYPES) {
        int t = threadIdx.x, s = 0, mb = 0;
        for (int c = 0; c < CHUNKS; ++c) {
            if (c == b) mb = s;
            s += ws[OFF_CC + c * N_TYPES + t];
        }
        tot[t] = s;
        mybase[t] = mb;
        lc[t] = 0;
    }
    __syncthreads();
    if (threadIdx.x == 0) {
        int off = 0;
        for (int t = 0; t < N_TYPES; ++t) {
            spoff[t] = off;
            off += ((tot[t] + BLK - 1) / BLK) * BLK;
        }
    }
    __syncthreads();
    if (threadIdx.x < N_TYPES) {
        sbase[threadIdx.x] = spoff[threadIdx.x] + mybase[threadIdx.x];
        if (b == 0) {                                       // publish for K3
            ws[OFF_COUNTS + threadIdx.x] = tot[threadIdx.x];
            ws[OFF_POFF + threadIdx.x]   = spoff[threadIdx.x];
        }
    }
    __syncthreads();
    int e0 = b * CH_SZ;
    int* sorted = ws + OFF_SORTED;
    for (int e = e0 + (int)threadIdx.x; e < e0 + CH_SZ; e += BLK) {
        int t = etype[e];
        int r = atomicAdd(&lc[t], 1);                       // LDS-local only
        sorted[sbase[t] + r] = e;
    }
}

// ---------- K3: sorted fp32 score + fused copy ----------
__device__ __forceinline__ void do_copy(const float* __restrict__ emb,
                                        float* __restrict__ out, int cb, int nb) {
    const f4* s4 = (const f4*)emb;
    f4* o4 = (f4*)(out + N_EDGES);
    const int n4 = N_NODES * EMB_DIM / 4;                   // 6.4M
    for (int i = cb * BLK + (int)threadIdx.x; i < n4; i += nb * BLK) {
        f4 a = s4[i];                                       // normal: warms LLC
        __builtin_nontemporal_store(a, &o4[i]);             // never re-read
    }
}

__device__ __forceinline__ void half_mm(const f4* __restrict__ x4,
                                        const float* __restrict__ w,
                                        float acc[HID]) {
#pragma unroll 1
    for (int c = 0; c < 4; ++c) {                           // 128B per chunk
        f4 r[8];
#pragma unroll
        for (int k = 0; k < 8; ++k) r[k] = x4[c * 8 + k];
#pragma unroll
        for (int k = 0; k < 8; ++k) {
            const float* wp = w + (c * 32 + k * 4) * HID;
#pragma unroll
            for (int j = 0; j < HID; ++j) acc[j] = fmaf(r[k][0], wp[0 * HID + j], acc[j]);
#pragma unroll
            for (int j = 0; j < HID; ++j) acc[j] = fmaf(r[k][1], wp[1 * HID + j], acc[j]);
#pragma unroll
            for (int j = 0; j < HID; ++j) acc[j] = fmaf(r[k][2], wp[2 * HID + j], acc[j]);
#pragma unroll
            for (int j = 0; j < HID; ++j) acc[j] = fmaf(r[k][3], wp[3 * HID + j], acc[j]);
        }
    }
}

__global__ __launch_bounds__(BLK) void score32_k(
        const float* __restrict__ emb,
        const int* __restrict__ srci, const int* __restrict__ dsti,
        const int* __restrict__ ws,
        const float* __restrict__ W1, const float* __restrict__ b1,
        const float* __restrict__ W2, const float* __restrict__ b2,
        float* __restrict__ out) {
    int b = blockIdx.x;
    if (b >= SCORE_BLOCKS) {
        do_copy(emb, out, b - SCORE_BLOCKS, (int)gridDim.x - SCORE_BLOCKS);
        return;
    }
    int poff[N_TYPES], counts[N_TYPES];
#pragma unroll
    for (int t = 0; t < N_TYPES; ++t) {
        counts[t] = ws[OFF_COUNTS + t];
        poff[t]   = ws[OFF_POFF + t];
    }
    int off = poff[N_TYPES - 1] + ((counts[N_TYPES - 1] + BLK - 1) / BLK) * BLK;
    int slot0 = b * BLK;
    if (slot0 >= off) return;
    int t = 0;
#pragma unroll
    for (int i = 1; i < N_TYPES; ++i)
        if (slot0 >= poff[i]) t = i;
    t = __builtin_amdgcn_readfirstlane(t);   // wave-uniform type -> scalar W loads
    int cnt = counts[t];
    int local = slot0 - poff[t] + (int)threadIdx.x;
    if (local >= cnt) return;
    const int* sorted = ws + OFF_SORTED;
    int e = sorted[slot0 + threadIdx.x];
    int s = srci[e], d = dsti[e];

    float acc[HID];
#pragma unroll
    for (int j = 0; j < HID; ++j) acc[j] = b1[t * HID + j];
    const float* W1t = W1 + (size_t)t * (2 * EMB_DIM * HID);
    half_mm((const f4*)(emb + (size_t)s * EMB_DIM), W1t, acc);
    half_mm((const f4*)(emb + (size_t)d * EMB_DIM), W1t + EMB_DIM * HID, acc);
    float sc = b2[t];
#pragma unroll
    for (int j = 0; j < HID; ++j) {
        float h = acc[j];
        h = (h > 0.f) ? h : 0.01f * h;       // LeakyReLU(0.01)
        sc = fmaf(h, W2[t * HID + j], sc);
    }
    out[e] = sc;
}

// ---------- ws-too-small fallback: correctness only ----------
__global__ __launch_bounds__(BLK) void fallback_k(
        const float* __restrict__ emb,
        const int* __restrict__ srci, const int* __restrict__ dsti,
        const int* __restrict__ etype,
        const float* __restrict__ W1, const float* __restrict__ b1,
        const float* __restrict__ W2, const float* __restrict__ b2,
        float* __restrict__ out) {
    long long i0 = (long long)blockIdx.x * BLK + threadIdx.x;
    const f4* s4 = (const f4*)emb;
    f4* o4 = (f4*)(out + N_EDGES);
    const long long n4 = (long long)N_NODES * EMB_DIM / 4;
    for (long long i = i0; i < n4; i += (long long)gridDim.x * BLK)
        o4[i] = s4[i];
    for (int e = (int)i0; e < N_EDGES; e += gridDim.x * BLK) {
        int t = etype[e];
        int s = srci[e], d = dsti[e];
        float acc[HID];
#pragma unroll
        for (int j = 0; j < HID; ++j) acc[j] = b1[t * HID + j];
        const float* w = W1 + (size_t)t * 2 * EMB_DIM * HID;
        half_mm((const f4*)(emb + (size_t)s * EMB_DIM), w, acc);
        half_mm((const f4*)(emb + (size_t)d * EMB_DIM), w + EMB_DIM * HID, acc);
        float sc = b2[t];
#pragma unroll
        for (int j = 0; j < HID; ++j) {
            float h = acc[j];
            h = (h > 0.f) ? h : 0.01f * h;
            sc = fmaf(h, W2[t * HID + j], sc);
        }
        out[e] = sc;
    }
}

extern "C" void kernel_launch(void* const* d_in, const int* in_sizes, int n_in,
                              void* d_out, int out_size, void* d_ws, size_t ws_size,
                              hipStream_t stream) {
    const float* emb   = (const float*)d_in[0];
    const int*   eidx  = (const int*)d_in[1];
    const int*   etype = (const int*)d_in[2];
    const float* W1    = (const float*)d_in[3];
    const float* b1    = (const float*)d_in[4];
    const float* W2    = (const float*)d_in[5];
    const float* b2    = (const float*)d_in[6];
    float* out = (float*)d_out;
    const int* srci = eidx;
    const int* dsti = eidx + N_EDGES;

    if (ws_size >= WS_NEED) {
        int* ws = (int*)d_ws;
        hist_k<<<CHUNKS, BLK, 0, stream>>>(etype, ws);
        scatter_k<<<CHUNKS, BLK, 0, stream>>>(etype, ws);
        score32_k<<<SCORE_BLOCKS + COPY_BLOCKS, BLK, 0, stream>>>(
            emb, srci, dsti, ws, W1, b1, W2, b2, out);
    } else {
        fallback_k<<<2048, BLK, 0, stream>>>(emb, srci, dsti, etype, W1, b1, W2, b2, out);
    }
}